// Round 1
// baseline (214.181 us; speedup 1.0000x reference)
//
#include <hip/hip_runtime.h>

// Conv2D 3x3 pad1 stride1: x(32,32,128,128) fp32 * w(64,32,3,3) + bias -> (32,64,128,128) fp32
// Strategy: bf16 MFMA implicit GEMM. Per block = one (batch n, output row h).
//   For each (kr,kc): GEMM  D[ok][w] += W[ok][c] * Xrow[c][w]   (K = C = 32, one
//   mfma_f32_16x16x32_bf16 per 16x16 tile).
// A-operand = weights  (m = lane&15 -> ok, k = quad*8+j -> c)
// B-operand = x row    (n = lane&15 -> w,  k = quad*8+j -> c)
// C/D: col = lane&15 -> w (coalesced stores), row = quad*4+reg -> ok.

typedef __attribute__((ext_vector_type(8))) short bf16x8;
typedef __attribute__((ext_vector_type(4))) float f32x4;

#define NB 32
#define CIN 32
#define HH 128
#define WW 128
#define NK 64

__device__ __forceinline__ unsigned short f2bf(float f) {
    union { float f; unsigned int u; } v; v.f = f;
    unsigned int u = v.u;
    return (unsigned short)((u + 0x7FFFu + ((u >> 16) & 1u)) >> 16);  // RNE
}

// LDS x tile: [wi 0..129][c 0..31] bf16, 16B-chunk XOR swizzle on (wi>>2)&3 so
// transpose writes (b32, lane-stride 4 rows) and frag reads (b128) spread banks.
__device__ __forceinline__ int xel(int wi, int c) {
    return wi * 32 + ((((c >> 3) ^ ((wi >> 2) & 3)) << 3) | (c & 7));
}
// LDS weights: [kidx 0..8][ok 0..63][c 0..31] bf16, chunk swizzled by ok&3.
__device__ __forceinline__ int wel(int kidx, int ok, int c) {
    return (kidx * 64 + ok) * 32 + ((((c >> 3) ^ (ok & 3)) << 3) | (c & 7));
}

__global__ __launch_bounds__(256) void conv3x3_mfma(
        const float* __restrict__ x, const float* __restrict__ kern,
        const float* __restrict__ bias, float* __restrict__ out) {
    __shared__ unsigned short lds_w[9 * 64 * 32];   // 36864 B
    __shared__ unsigned short lds_x[130 * 32];      //  8320 B

    const int tid = threadIdx.x;
    const int h = blockIdx.x;
    const int n = blockIdx.y;
    const int lane = tid & 63;
    const int l16 = lane & 15;
    const int q = lane >> 4;            // 0..3
    const int wav = tid >> 6;           // 0..3
    const int ok_base = (wav & 1) * 32; // wave covers ok ok_base..+31 (2 subtiles)
    const int w_base = (wav >> 1) * 64; // wave covers w  w_base..+63  (4 subtiles)

    // ---- stage weights: kern[ok][c*9 + kr*3 + kc] fp32 -> lds_w bf16 ----
    {
        const float4* k4 = (const float4*)kern;
        #pragma unroll
        for (int i = 0; i < 18; ++i) {          // 18432 elems / 256 thr / 4
            int u = tid + i * 256;
            float4 v = k4[u];
            int g = u * 4;
            #pragma unroll
            for (int j = 0; j < 4; ++j) {
                int gg = g + j;
                int ok = gg / 288;
                int rem = gg - ok * 288;
                int c = rem / 9;
                int kidx = rem - c * 9;
                lds_w[wel(kidx, ok, c)] = f2bf((&v.x)[j]);
            }
        }
    }
    // zero halo columns wi=0 (w=-1) and wi=129 (w=128)
    if (tid < 64) {
        int c = tid & 31;
        int wi = (tid < 32) ? 0 : 129;
        lds_x[xel(wi, c)] = 0;
    }

    f32x4 acc[2][4];
    #pragma unroll
    for (int mi = 0; mi < 2; ++mi)
        #pragma unroll
        for (int ni = 0; ni < 4; ++ni)
            acc[mi][ni] = (f32x4){0.f, 0.f, 0.f, 0.f};

    for (int kr = 0; kr < 3; ++kr) {
        const int r = h + kr - 1;
        if (r < 0 || r >= HH) continue;        // whole row is zero padding
        __syncthreads();                        // protect lds_x from prior iter
        // ---- stage input row r, transposed [w][c], fp32 -> bf16 packed b32 ----
        #pragma unroll
        for (int it = 0; it < 2; ++it) {
            int u = it * 256 + tid;             // 0..511
            int c = (u >> 5) * 2;               // even channel 0..30
            int wq = u & 31;                    // float4 index along w
            const float4* pa = (const float4*)(x + ((n * CIN + c) * HH + r) * WW) + wq;
            const float4* pb = (const float4*)(x + ((n * CIN + c + 1) * HH + r) * WW) + wq;
            float4 va = *pa;
            float4 vb = *pb;
            #pragma unroll
            for (int j = 0; j < 4; ++j) {
                int w = wq * 4 + j;
                unsigned int pk = (unsigned int)f2bf((&va.x)[j]) |
                                  ((unsigned int)f2bf((&vb.x)[j]) << 16);
                *(unsigned int*)&lds_x[xel(w + 1, c)] = pk;  // c even -> 4B aligned
            }
        }
        __syncthreads();
        // ---- 3 kc positions, each one K=32 MFMA per (ok,w) tile ----
        #pragma unroll
        for (int kc = 0; kc < 3; ++kc) {
            const int kidx = kr * 3 + kc;
            bf16x8 afr[2];
            #pragma unroll
            for (int mi = 0; mi < 2; ++mi)
                afr[mi] = *(const bf16x8*)&lds_w[wel(kidx, ok_base + mi * 16 + l16, q * 8)];
            #pragma unroll
            for (int ni = 0; ni < 4; ++ni) {
                bf16x8 bfr = *(const bf16x8*)&lds_x[xel(w_base + ni * 16 + l16 + kc, q * 8)];
                #pragma unroll
                for (int mi = 0; mi < 2; ++mi)
                    acc[mi][ni] = __builtin_amdgcn_mfma_f32_16x16x32_bf16(
                        afr[mi], bfr, acc[mi][ni], 0, 0, 0);
            }
        }
    }

    // ---- epilogue: + bias, store. 16 consecutive w per 16-lane group. ----
    #pragma unroll
    for (int mi = 0; mi < 2; ++mi) {
        #pragma unroll
        for (int rg = 0; rg < 4; ++rg) {
            int ok = ok_base + mi * 16 + q * 4 + rg;
            float bv = bias[ok];
            float* orow = out + ((size_t)(n * NK + ok) * HH + h) * WW;
            #pragma unroll
            for (int ni = 0; ni < 4; ++ni)
                orow[w_base + ni * 16 + l16] = acc[mi][ni][rg] + bv;
        }
    }
}

extern "C" void kernel_launch(void* const* d_in, const int* in_sizes, int n_in,
                              void* d_out, int out_size, void* d_ws, size_t ws_size,
                              hipStream_t stream) {
    const float* x    = (const float*)d_in[0];
    const float* kern = (const float*)d_in[1];
    const float* bias = (const float*)d_in[2];
    float* out = (float*)d_out;
    dim3 grid(HH, NB);  // (output row, batch)
    conv3x3_mfma<<<grid, 256, 0, stream>>>(x, kern, bias, out);
}

// Round 2
// 197.707 us; speedup vs baseline: 1.0833x; 1.0833x over previous
//
#include <hip/hip_runtime.h>
#include <hip/hip_bf16.h>

// Conv2D 3x3 pad1 stride1: x(32,32,128,128) fp32 * w(64,32,3,3) + bias -> (32,64,128,128) fp32
// bf16 MFMA implicit GEMM. Block = one (batch n, output row h).
// Per (kr,kc): D[ok][w] += W[ok][c] * Xrow[c][w], K=C=32, mfma_f32_16x16x32_bf16.
// Round 2: weights pre-packed to A-frag order in d_ws by a pre-kernel (kills the
// per-block div/mod+ds_write storm that made VALUBusy 54%); all 3 x rows staged
// with a single barrier; h swizzled so same-XCD blocks share x rows in L2.

typedef __attribute__((ext_vector_type(8))) short bf16x8;
typedef __attribute__((ext_vector_type(4))) float f32x4;

#define NB 32
#define CIN 32
#define HH 128
#define WW 128
#define NK 64
#define XROW (130 * 32)   // one LDS x row: wi 0..129 (halo), c 0..31

__device__ __forceinline__ unsigned short f2bf(float f) {
    union { float f; unsigned int u; } v; v.f = f;
    unsigned int u = v.u;
    return (unsigned short)((u + 0x7FFFu + ((u >> 16) & 1u)) >> 16);  // RNE
}

// LDS x tile element: [wi][c] bf16, 16B-chunk XOR swizzle so transpose writes
// (b32) and frag reads (b128) spread across banks.
__device__ __forceinline__ int xel(int wi, int c) {
    return wi * 32 + ((((c >> 3) ^ ((wi >> 2) & 3)) << 3) | (c & 7));
}

// Pre-kernel: kern[ok][c*9+kidx] fp32 -> wfrag bf16 in A-fragment order:
// wfrag[((kidx*4 + tile)*64 + lane)*8 + j], ok = tile*16 + (lane&15), c = (lane>>4)*8 + j.
__global__ void repack_w(const float* __restrict__ kern,
                         unsigned short* __restrict__ wfrag) {
    int u = blockIdx.x * 256 + threadIdx.x;      // 0..18431
    int j = u & 7;
    int lane = (u >> 3) & 63;
    int tile = (u >> 9) & 3;
    int kidx = u >> 11;
    int ok = tile * 16 + (lane & 15);
    int c = ((lane >> 4) << 3) + j;
    wfrag[u] = f2bf(kern[ok * 288 + c * 9 + kidx]);
}

__global__ __launch_bounds__(256, 4) void conv3x3_mfma(
        const float* __restrict__ x, const unsigned short* __restrict__ wfrag,
        const float* __restrict__ bias, float* __restrict__ out) {
    __shared__ unsigned short lds_x[3 * XROW];   // 24960 B

    const int tid = threadIdx.x;
    const int bx = blockIdx.x;
    // XCD swizzle: round-robin dispatch puts bid%8 on XCD bid%8; give each XCD
    // a contiguous h range so h-adjacent blocks (sharing 2 of 3 x rows) hit the
    // same XCD's L2.
    const int h = ((bx & 7) << 4) | (bx >> 3);
    const int n = blockIdx.y;
    const int lane = tid & 63;
    const int l16 = lane & 15;
    const int q = lane >> 4;            // 0..3
    const int wav = tid >> 6;           // 0..3
    const int ok_tile = (wav & 1) * 2;  // A-frag tiles ok_tile, ok_tile+1
    const int w_base = (wav >> 1) * 64; // wave covers w w_base..+63

    // halo zeros (wi=0 -> w=-1, wi=129 -> w=128) for all 3 row buffers
    if (tid < 192) {
        int kr = tid >> 6;
        int idx = tid & 63;
        int c = idx & 31;
        int wi = (idx < 32) ? 0 : 129;
        lds_x[kr * XROW + xel(wi, c)] = 0;
    }

    // ---- stage rows h-1, h, h+1 transposed [w][c] fp32->bf16 ----
    #pragma unroll
    for (int kr = 0; kr < 3; ++kr) {
        const int r = h + kr - 1;
        const bool valid = (unsigned)r < HH;
        const float* xrow = x + ((size_t)(n * CIN) * HH + r) * WW;
        unsigned short* lrow = lds_x + kr * XROW;
        #pragma unroll
        for (int it = 0; it < 2; ++it) {
            int u = it * 256 + tid;             // 0..511
            int c = (u >> 5) * 2;               // even channel
            int wq = u & 31;                    // float4 index along w
            float4 va = {0.f, 0.f, 0.f, 0.f}, vb = {0.f, 0.f, 0.f, 0.f};
            if (valid) {
                va = *((const float4*)(xrow + (size_t)c * HH * WW) + wq);
                vb = *((const float4*)(xrow + (size_t)(c + 1) * HH * WW) + wq);
            }
            #pragma unroll
            for (int j = 0; j < 4; ++j) {
                int w = wq * 4 + j;
                __hip_bfloat162 h2 = __float22bfloat162_rn(
                    make_float2((&va.x)[j], (&vb.x)[j]));
                *(unsigned int*)&lrow[xel(w + 1, c)] = *(unsigned int*)&h2;
            }
        }
    }
    __syncthreads();

    f32x4 acc[2][4];
    #pragma unroll
    for (int mi = 0; mi < 2; ++mi)
        #pragma unroll
        for (int ni = 0; ni < 4; ++ni)
            acc[mi][ni] = (f32x4){0.f, 0.f, 0.f, 0.f};

    #pragma unroll 1   // keep VGPR pressure down -> 4 blocks/CU
    for (int kr = 0; kr < 3; ++kr) {
        const unsigned short* lrow = lds_x + kr * XROW;
        #pragma unroll
        for (int kc = 0; kc < 3; ++kc) {
            const int kidx = kr * 3 + kc;
            bf16x8 afr[2];
            #pragma unroll
            for (int mi = 0; mi < 2; ++mi)
                afr[mi] = *(const bf16x8*)
                    &wfrag[(size_t)(((kidx * 4) + ok_tile + mi) * 64 + lane) * 8];
            #pragma unroll
            for (int ni = 0; ni < 4; ++ni) {
                bf16x8 bfr = *(const bf16x8*)&lrow[xel(w_base + ni * 16 + l16 + kc, q * 8)];
                #pragma unroll
                for (int mi = 0; mi < 2; ++mi)
                    acc[mi][ni] = __builtin_amdgcn_mfma_f32_16x16x32_bf16(
                        afr[mi], bfr, acc[mi][ni], 0, 0, 0);
            }
        }
    }

    // ---- epilogue: + bias, coalesced stores (16 consecutive w per 16-lane group) ----
    #pragma unroll
    for (int mi = 0; mi < 2; ++mi) {
        #pragma unroll
        for (int rg = 0; rg < 4; ++rg) {
            int ok = (wav & 1) * 32 + mi * 16 + q * 4 + rg;
            float bv = bias[ok];
            float* orow = out + ((size_t)(n * NK + ok) * HH + h) * WW;
            #pragma unroll
            for (int ni = 0; ni < 4; ++ni)
                orow[w_base + ni * 16 + l16] = acc[mi][ni][rg] + bv;
        }
    }
}

extern "C" void kernel_launch(void* const* d_in, const int* in_sizes, int n_in,
                              void* d_out, int out_size, void* d_ws, size_t ws_size,
                              hipStream_t stream) {
    const float* x    = (const float*)d_in[0];
    const float* kern = (const float*)d_in[1];
    const float* bias = (const float*)d_in[2];
    float* out = (float*)d_out;
    unsigned short* wfrag = (unsigned short*)d_ws;   // 18432 bf16 = 36864 B

    repack_w<<<72, 256, 0, stream>>>(kern, wfrag);
    dim3 grid(HH, NB);  // (swizzled output row, batch)
    conv3x3_mfma<<<grid, 256, 0, stream>>>(x, wfrag, bias, out);
}